// Round 16
// baseline (233.668 us; speedup 1.0000x reference)
//
#include <hip/hip_runtime.h>
#include <hip/hip_bf16.h>
#include <cstdint>

#define BATCH   2048
#define INDIM   256
#define OUTDIM  256
#define KGRID   300   // fourier modes k = 1..300
#define NCHUNK  10    // chunks of 32 k (last padded)
#define JLDS    224   // j < 224 staged via DMA->LDS; j >= 224 global->reg

typedef __attribute__((ext_vector_type(4))) float f32x4;
typedef __attribute__((ext_vector_type(2))) float f32x2;
typedef __attribute__((ext_vector_type(8))) short bf16x8;

__device__ __forceinline__ uint32_t pack_bf16x2(float lo, float hi) {
    union { __hip_bfloat162 h; uint32_t u; } cv;
    cv.h = __float22bfloat162_rn(make_float2(lo, hi));
    return cv.u;
}

__device__ __forceinline__ float bfu2f(unsigned short u) {
    union { unsigned short s[2]; float f; } c; c.s[0] = 0; c.s[1] = u; return c.f;
}

// packed fp32x2 FMA with negated addend: d = a*b - c   (one VOP3P instr)
__device__ __forceinline__ f32x2 pk_fma_sub(f32x2 a, f32x2 b, f32x2 c) {
    f32x2 d;
    asm("v_pk_fma_f32 %0, %1, %2, %3 neg_lo:[0,0,1] neg_hi:[0,0,1]"
        : "=v"(d) : "v"(a), "v"(b), "v"(c));
    return d;
}

__device__ __forceinline__ void load_lds16(const void* g, void* l) {
    __builtin_amdgcn_global_load_lds(
        (const __attribute__((address_space(1))) void*)g,
        (__attribute__((address_space(3))) void*)l, 16, 0, 0);
}

__device__ __forceinline__ bf16x8 zero_frag() {
    union { uint32_t u[4]; bf16x8 v; } z = {{0u, 0u, 0u, 0u}};
    return z.v;
}

// Generate one A-fragment: 4 consecutive k of (cos,sin) bf16 pairs starting
// at seed (ck,sk); Chebyshev forward recurrence with T2 = 2 cos(theta).
__device__ __forceinline__ bf16x8 gen_frag(float ck, float sk,
                                           float c1, float s1) {
    float cp = __builtin_fmaf(ck, c1,  sk * s1);   // value at k-1
    float sp = __builtin_fmaf(sk, c1, -ck * s1);
    f32x2 C; C.x = ck; C.y = sk;
    f32x2 P; P.x = cp; P.y = sp;
    f32x2 T2; T2.x = c1 + c1; T2.y = c1 + c1;
    union { uint32_t u[4]; bf16x8 v; } r;
    #pragma unroll
    for (int q = 0; q < 4; ++q) {
        r.u[q] = pack_bf16x2(C.x, C.y);
        f32x2 N = pk_fma_sub(T2, C, P);
        P = C; C = N;
    }
    return r.v;
}

// Packed coeff tensor, two regions:
//  L (j < 224): [i][ch][j][sub] uint4, LDS-swizzled (sub ^ (j & 7)) for
//     linear global_load_lds staging + swizzled ds_read.
//  H (j >= 224): fragment-major [i][ch][s(2)][jb(2)][lane(64)] uint4 — one
//     MFMA B-fragment = 64 consecutive uint4 = 1 KB contiguous, read
//     global->register. All 4 H-fragment loads are issued BEFORE the DMA
//     (r14's bug was the s=1 reload issued after -> its wait drained the
//     DMA); consuming them now needs only vmcnt>=7, DMA stays in flight.
#define PKL_U4 ((size_t)INDIM * NCHUNK * JLDS * 8)        // 4,587,520
#define PKH_U4 ((size_t)INDIM * NCHUNK * 256)             // 655,360
#define PKL_BYTES (PKL_U4 * 16)                           // 73.4 MB
#define PKH_BYTES (PKH_U4 * 16)                           // 10.5 MB
#define PART_BYTES ((size_t)32 * BATCH * OUTDIM * 2)      // bf16, 33.5 MB

// ---------------------------------------------------------------------------
// Kernel 0: pack fc (fp32 [2][j][i][k]) -> bf16 regions L and H
// ---------------------------------------------------------------------------
__global__ __launch_bounds__(256) void pack_kernel(
    const float* __restrict__ fc, uint4* __restrict__ pkl,
    uint4* __restrict__ pkh)
{
    size_t tidg = (size_t)blockIdx.x * 256 + threadIdx.x;   // one uint4 each
    if (tidg < PKL_U4) {
        int sub = (int)(tidg & 7);
        size_t rem = tidg >> 3;
        int j   = (int)(rem % JLDS);
        int ich = (int)(rem / JLDS);
        int ch  = ich % NCHUNK;
        int i   = ich / NCHUNK;
        int kb  = ch * 32 + (sub ^ (j & 7)) * 4;
        if (kb > KGRID - 4) kb = KGRID - 4;   // clamp; A=0 kills padded kk
        const float* pc = fc + ((size_t)j * INDIM + i) * KGRID + kb;
        const float* ps = pc + (size_t)OUTDIM * INDIM * KGRID;
        float4 vc = *reinterpret_cast<const float4*>(pc);
        float4 vs = *reinterpret_cast<const float4*>(ps);
        uint4 wv;
        wv.x = pack_bf16x2(vc.x, vs.x);
        wv.y = pack_bf16x2(vc.y, vs.y);
        wv.z = pack_bf16x2(vc.z, vs.z);
        wv.w = pack_bf16x2(vc.w, vs.w);
        pkl[tidg] = wv;
    } else {
        size_t e = tidg - PKL_U4;
        int lane = (int)(e & 63);
        int jb  = (int)(e >> 6) & 1;
        int s   = (int)(e >> 7) & 1;
        int ich = (int)(e >> 8);
        int ch  = ich % NCHUNK;
        int i   = ich / NCHUNK;
        int j   = JLDS + jb * 16 + (lane & 15);
        int kb  = ch * 32 + s * 16 + (lane >> 4) * 4;
        if (kb > KGRID - 4) kb = KGRID - 4;
        const float* pc = fc + ((size_t)j * INDIM + i) * KGRID + kb;
        const float* ps = pc + (size_t)OUTDIM * INDIM * KGRID;
        float4 vc = *reinterpret_cast<const float4*>(pc);
        float4 vs = *reinterpret_cast<const float4*>(ps);
        uint4 wv;
        wv.x = pack_bf16x2(vc.x, vs.x);
        wv.y = pack_bf16x2(vc.y, vs.y);
        wv.z = pack_bf16x2(vc.z, vs.z);
        wv.w = pack_bf16x2(vc.w, vs.w);
        pkh[e] = wv;
    }
}

// ---------------------------------------------------------------------------
// Kernel 1 (main): fourier partials via MFMA. Round-15 kernel (128 b-rows x
// 256 j, 4 waves of 32 rows x 256 j, in-register A-gen, single barrier/iter,
// bf16 partials) with CORRECTED hybrid B: j<224 DMA->LDS (56 KB dbuf, 7
// loads/thread), j in [224,256) via 4 global->reg fragment loads issued
// right after the barrier, BEFORE the DMA (oldest in the vmcnt stream ->
// consuming them never drains the DMA). LDS reads 32->28, DMA writes
// 64->56 KB per CU-iter (~-12% on the binding LDS pipe).
// Grid 16 x 1 x 32 = 512 blocks (XCD-chunked swizzle), 2 blocks/CU.
// ---------------------------------------------------------------------------
__global__ __launch_bounds__(256, 2) void fourier_dma_kernel(
    const float* __restrict__ x, const uint4* __restrict__ pkl,
    const uint4* __restrict__ pkh, __hip_bfloat16* __restrict__ part)
{
    __shared__ uint4 Bbuf[2][JLDS][8];  // 56 KiB double-buffered DMA dest

    const int tid = threadIdx.x;
    // XCD-chunked bijective remap (512 = 8 XCD x 64)
    const int flat = blockIdx.x + (blockIdx.z << 4);
    const int L  = (flat & 7) * 64 + (flat >> 3);
    const int b0 = (L & 15) * 128;
    const int z  = L >> 4;              // i-split 0..31
    const int i0 = z * 8;

    const int lane = tid & 63, wave = tid >> 6;
    const int wrow = wave * 32;         // this wave's first b-row in block
    const int lrow = lane & 15, lgrp = lane >> 4;
    const int q7 = wave * 7;            // this wave's 7 DMA issues

    f32x4 acc[2][16] = {};              // [mf][nf], 128 regs

    // per-row (mf) generator state
    float thn[2];                       // prefetched theta for current/next il
    float c1[2], s1[2];                 // sincos(theta)
    float c16[2], s16[2];               // sincos(16 theta)
    float cS[2], sS[2];                 // running seed

    #pragma unroll
    for (int mf = 0; mf < 2; ++mf)
        thn[mf] = x[(size_t)(b0 + wrow + mf * 16 + lrow) * INDIM + i0];

    // prologue: DMA B-L(il=0, ch=0) into Bbuf[0]
    {
        const uint4* src = pkl + (size_t)(i0 * NCHUNK) * (JLDS * 8);
        char* dst = (char*)&Bbuf[0][0][0];
        #pragma unroll
        for (int q = 0; q < 7; ++q)
            load_lds16(src + (q7 + q) * 64 + lane, dst + (q7 + q) * 1024);
    }

    int il = 0, ch = 0;
    #pragma unroll 1
    for (int t = 0; t < 8 * NCHUNK; ++t) {
        // ---- single barrier: drains DMA(t), releases buf[(t+1)&1] ----
        __syncthreads();
        // ---- hi-j fragment loads for tile t, BEFORE the DMA (oldest) ----
        const uint4* hsrc = pkh + ((size_t)(i0 + il) * NCHUNK + ch) * 256;
        uint4 h0 = hsrc[lane];          // s=0, jb=0
        uint4 h1 = hsrc[ 64 + lane];    // s=0, jb=1
        uint4 h2 = hsrc[128 + lane];    // s=1, jb=0
        uint4 h3 = hsrc[192 + lane];    // s=1, jb=1
        // ---- issue DMA for t+1 (in flight across A-gen + MFMA) ----
        {
            int il2 = il, ch2 = ch + 1;
            if (ch2 == NCHUNK) { ch2 = 0; il2 = (il + 1 < 8) ? il + 1 : il; }
            const uint4* src =
                pkl + (size_t)((i0 + il2) * NCHUNK + ch2) * (JLDS * 8);
            char* dst = (char*)&Bbuf[(t + 1) & 1][0][0];
            #pragma unroll
            for (int q = 0; q < 7; ++q)
                load_lds16(src + (q7 + q) * 64 + lane, dst + (q7 + q) * 1024);
        }
        // ---- per-il seed init (every 10th iter) ----
        if (ch == 0) {
            const float flg = (float)(lgrp * 4);
            #pragma unroll
            for (int mf = 0; mf < 2; ++mf) {
                float th = thn[mf];
                __sincosf(th, &s1[mf], &c1[mf]);
                __sincosf(16.f * th, &s16[mf], &c16[mf]);
                float a0 = __builtin_fmaf(flg, th, th);   // (lgrp*4+1)*theta
                __sincosf(a0, &sS[mf], &cS[mf]);
            }
            int iln = (il + 1 < 8) ? il + 1 : il;         // prefetch next theta
            #pragma unroll
            for (int mf = 0; mf < 2; ++mf)
                thn[mf] = x[(size_t)(b0 + wrow + mf * 16 + lrow) * INDIM
                            + i0 + iln];
        }
        // ---- A-gen: 4 fragments in registers (2 rows x 2 k-halves) ----
        bf16x8 af[2][2];                 // [s][mf]
        #pragma unroll
        for (int mf = 0; mf < 2; ++mf) {
            af[0][mf] = gen_frag(cS[mf], sS[mf], c1[mf], s1[mf]);
            float ck = __builtin_fmaf(cS[mf], c16[mf], -sS[mf] * s16[mf]);
            float sk = __builtin_fmaf(sS[mf], c16[mf],  cS[mf] * s16[mf]);
            af[1][mf] = gen_frag(ck, sk, c1[mf], s1[mf]);
            // advance seed to next chunk: rotate by 16*theta again (=32 total)
            cS[mf] = __builtin_fmaf(ck, c16[mf], -sk * s16[mf]);
            sS[mf] = __builtin_fmaf(sk, c16[mf],  ck * s16[mf]);
        }
        if (ch == NCHUNK - 1) {          // zero padded k >= 300
            #pragma unroll
            for (int mf = 0; mf < 2; ++mf) {
                af[0][mf] = (lgrp == 3) ? zero_frag() : af[0][mf];
                af[1][mf] = zero_frag();  // k >= 304 entirely
            }
        }
        // ---- 64 MFMA on tile t ----
        __builtin_amdgcn_s_setprio(1);
        #pragma unroll
        for (int s = 0; s < 2; ++s) {
            const int swz = (s * 4 + lgrp) ^ (lrow & 7);
            #pragma unroll
            for (int g = 0; g < 4; ++g) {
                bf16x8 bfr[4];
                #pragma unroll
                for (int q = 0; q < 4; ++q) {
                    const int f = g * 4 + q;
                    uint4 tv;
                    if (f < 14) {
                        tv = Bbuf[t & 1][f * 16 + lrow][swz];
                    } else {
                        tv = (s == 0) ? ((f == 14) ? h0 : h1)
                                      : ((f == 14) ? h2 : h3);
                    }
                    bfr[q] = *reinterpret_cast<bf16x8*>(&tv);
                }
                #pragma unroll
                for (int mf = 0; mf < 2; ++mf)
                    #pragma unroll
                    for (int q = 0; q < 4; ++q)
                        acc[mf][g * 4 + q] = __builtin_amdgcn_mfma_f32_16x16x32_bf16(
                            af[s][mf], bfr[q], acc[mf][g * 4 + q], 0, 0, 0);
            }
        }
        __builtin_amdgcn_s_setprio(0);
        if (++ch == NCHUNK) { ch = 0; ++il; }
    }

    // epilogue: per-split bf16 partial tile (single writer per element)
    __hip_bfloat16* pws = part + (size_t)z * BATCH * OUTDIM;
    #pragma unroll
    for (int mf = 0; mf < 2; ++mf)
        #pragma unroll
        for (int nf = 0; nf < 16; ++nf)
            #pragma unroll
            for (int r = 0; r < 4; ++r) {
                int b = b0 + wrow + mf * 16 + lgrp * 4 + r;
                int j = nf * 16 + lrow;
                pws[(size_t)b * OUTDIM + j] = __float2bfloat16(acc[mf][nf][r]);
            }
}

// ---------------------------------------------------------------------------
// Fallback fourier kernel (round-2, reg-staged from fc): ws too small.
// ---------------------------------------------------------------------------
__global__ __launch_bounds__(256, 2) void fourier_kernel_fb(
    const float* __restrict__ x, const float* __restrict__ fc,
    __hip_bfloat16* __restrict__ ws, int ips)
{
    __shared__ uint4 Abuf[2][128][8];
    __shared__ uint4 Bbuf[128][8];

    const int tid  = threadIdx.x;
    const int b0   = blockIdx.x * 256;
    const int j0   = blockIdx.y * 128;
    const int i0   = blockIdx.z * ips;

    const int lane = tid & 63, wave = tid >> 6;
    const int wm   = wave >> 1, wn = wave & 1;
    const int lrow = lane & 15, lgrp = lane >> 4;
    const int grow = tid >> 1,  gh = tid & 1;

    f32x4 acc[2][4][4] = {};

    #pragma unroll 1
    for (int il = 0; il < ips; ++il) {
        const int i = i0 + il;
        float th[2], c1[2], s1[2], t2[2];
        th[0] = x[(size_t)(b0 + grow)       * INDIM + i];
        th[1] = x[(size_t)(b0 + 128 + grow) * INDIM + i];
        #pragma unroll
        for (int m = 0; m < 2; ++m) {
            __sincosf(th[m], &s1[m], &c1[m]);
            t2[m] = 2.f * c1[m];
        }
        #pragma unroll 1
        for (int ch = 0; ch < NCHUNK; ++ch) {
            #pragma unroll
            for (int r = 0; r < 4; ++r) {
                int flat = r * 256 + tid;
                int jl = flat >> 3, sub = flat & 7;
                int kb = ch * 32 + sub * 4;
                if (kb > KGRID - 4) kb = KGRID - 4;
                const float* pc = fc + ((size_t)(j0 + jl) * INDIM + i) * KGRID + kb;
                const float* ps = pc + (size_t)OUTDIM * INDIM * KGRID;
                float4 vc = *reinterpret_cast<const float4*>(pc);
                float4 vs = *reinterpret_cast<const float4*>(ps);
                uint4 wv;
                wv.x = pack_bf16x2(vc.x, vs.x);
                wv.y = pack_bf16x2(vc.y, vs.y);
                wv.z = pack_bf16x2(vc.z, vs.z);
                wv.w = pack_bf16x2(vc.w, vs.w);
                Bbuf[jl][sub ^ (jl & 7)] = wv;
            }
            #pragma unroll
            for (int m = 0; m < 2; ++m) {
                const int k0 = ch * 32 + gh * 16;
                float ck, sk;
                __sincosf(th[m] * (float)(k0 + 1), &sk, &ck);
                float cp = __builtin_fmaf(ck, c1[m],  sk * s1[m]);
                float sp = __builtin_fmaf(sk, c1[m], -ck * s1[m]);
                const int swz = grow & 7;
                #pragma unroll
                for (int c = 0; c < 4; ++c) {
                    uint32_t uu[4];
                    #pragma unroll
                    for (int qq = 0; qq < 4; ++qq) {
                        const int kidx = k0 + c * 4 + qq;
                        float cc = (kidx < KGRID) ? ck : 0.f;
                        float ss = (kidx < KGRID) ? sk : 0.f;
                        uu[qq] = pack_bf16x2(cc, ss);
                        float cn = __builtin_fmaf(t2[m], ck, -cp);
                        float sn = __builtin_fmaf(t2[m], sk, -sp);
                        cp = ck; sp = sk; ck = cn; sk = sn;
                    }
                    Abuf[m][grow][(gh * 4 + c) ^ swz] =
                        make_uint4(uu[0], uu[1], uu[2], uu[3]);
                }
            }
            __syncthreads();
            #pragma unroll
            for (int s = 0; s < 2; ++s) {
                bf16x8 bfr[4];
                #pragma unroll
                for (int nf = 0; nf < 4; ++nf) {
                    const int jl = wn * 64 + nf * 16 + lrow;
                    uint4 tv = Bbuf[jl][(s * 4 + lgrp) ^ (jl & 7)];
                    bfr[nf] = *reinterpret_cast<bf16x8*>(&tv);
                }
                #pragma unroll
                for (int m = 0; m < 2; ++m) {
                    #pragma unroll
                    for (int mf = 0; mf < 4; ++mf) {
                        const int rowA = wm * 64 + mf * 16 + lrow;
                        uint4 tv = Abuf[m][rowA][(s * 4 + lgrp) ^ (rowA & 7)];
                        bf16x8 af = *reinterpret_cast<bf16x8*>(&tv);
                        #pragma unroll
                        for (int nf = 0; nf < 4; ++nf)
                            acc[m][mf][nf] = __builtin_amdgcn_mfma_f32_16x16x32_bf16(
                                af, bfr[nf], acc[m][mf][nf], 0, 0, 0);
                    }
                }
            }
            __syncthreads();
        }
    }

    __hip_bfloat16* pws = ws + (size_t)blockIdx.z * BATCH * OUTDIM;
    #pragma unroll
    for (int m = 0; m < 2; ++m)
        #pragma unroll
        for (int mf = 0; mf < 4; ++mf)
            #pragma unroll
            for (int nf = 0; nf < 4; ++nf)
                #pragma unroll
                for (int r = 0; r < 4; ++r) {
                    int b = b0 + m * 128 + wm * 64 + mf * 16 + lgrp * 4 + r;
                    int j = j0 + wn * 64 + nf * 16 + lrow;
                    pws[(size_t)b * OUTDIM + j] =
                        __float2bfloat16(acc[m][mf][nf][r]);
                }
}

// ---------------------------------------------------------------------------
// Kernel 2: out[b,j] = silu(x[b,:] @ W[:,j]) + sum_s part[s][b][j]  (bf16)
// ---------------------------------------------------------------------------
__global__ __launch_bounds__(256) void combine_kernel(
    const float* __restrict__ x, const float* __restrict__ w,
    const __hip_bfloat16* __restrict__ part, float* __restrict__ out,
    int nsplit)
{
    __shared__ float Xs[64][16];
    __shared__ float Wt[16][68];

    const int tid = threadIdx.x;
    const int b0 = blockIdx.x * 64;
    const int j0 = blockIdx.y * 64;
    const int tx = tid & 15, ty = tid >> 4;

    float acc[4][4] = {};

    for (int kb = 0; kb < INDIM; kb += 16) {
        {
            int m = tid >> 2, kq = (tid & 3) * 4;
            float4 v = *reinterpret_cast<const float4*>(
                &x[(size_t)(b0 + m) * INDIM + kb + kq]);
            Xs[m][kq+0] = v.x; Xs[m][kq+1] = v.y; Xs[m][kq+2] = v.z; Xs[m][kq+3] = v.w;
        }
        {
            int kr = tid >> 4, jc = (tid & 15) * 4;
            float4 v = *reinterpret_cast<const float4*>(
                &w[(size_t)(kb + kr) * OUTDIM + j0 + jc]);
            Wt[kr][jc+0] = v.x; Wt[kr][jc+1] = v.y; Wt[kr][jc+2] = v.z; Wt[kr][jc+3] = v.w;
        }
        __syncthreads();
        #pragma unroll
        for (int kk = 0; kk < 16; ++kk) {
            float a[4], b[4];
            #pragma unroll
            for (int q = 0; q < 4; ++q) { a[q] = Xs[ty*4+q][kk]; b[q] = Wt[kk][tx*4+q]; }
            #pragma unroll
            for (int q = 0; q < 4; ++q)
                #pragma unroll
                for (int p = 0; p < 4; ++p)
                    acc[q][p] = __builtin_fmaf(a[q], b[p], acc[q][p]);
        }
        __syncthreads();
    }

    float psum[4][4] = {};
    for (int s = 0; s < nsplit; ++s) {
        const __hip_bfloat16* base = part + (size_t)s * BATCH * OUTDIM;
        #pragma unroll
        for (int q = 0; q < 4; ++q) {
            ushort4 pv = *reinterpret_cast<const ushort4*>(
                &base[(size_t)(b0 + ty*4 + q) * OUTDIM + j0 + tx*4]);
            psum[q][0] += bfu2f(pv.x); psum[q][1] += bfu2f(pv.y);
            psum[q][2] += bfu2f(pv.z); psum[q][3] += bfu2f(pv.w);
        }
    }

    #pragma unroll
    for (int q = 0; q < 4; ++q)
        #pragma unroll
        for (int p = 0; p < 4; ++p) {
            float v = acc[q][p];
            float sv = v / (1.f + __expf(-v));
            out[(size_t)(b0 + ty*4 + q) * OUTDIM + (j0 + tx*4 + p)] =
                sv + psum[q][p];
        }
}

// ---------------------------------------------------------------------------
extern "C" void kernel_launch(void* const* d_in, const int* in_sizes, int n_in,
                              void* d_out, int out_size, void* d_ws, size_t ws_size,
                              hipStream_t stream) {
    const float* x  = (const float*)d_in[0];   // [2048, 256]
    const float* bw = (const float*)d_in[1];   // [256, 256]
    const float* fc = (const float*)d_in[2];   // [2, 256, 256, 300]
    float* out = (float*)d_out;                // [2048, 256]

    const size_t per = (size_t)BATCH * OUTDIM * 2;   // 1 MB/split (bf16)

    if (ws_size >= PKL_BYTES + PKH_BYTES + PART_BYTES) {
        // main path: pack -> hybrid fourier -> combine
        uint4* pkl = (uint4*)d_ws;
        uint4* pkh = (uint4*)((char*)d_ws + PKL_BYTES);
        __hip_bfloat16* part =
            (__hip_bfloat16*)((char*)d_ws + PKL_BYTES + PKH_BYTES);
        pack_kernel<<<(int)((PKL_U4 + PKH_U4) / 256), 256, 0, stream>>>(
            fc, pkl, pkh);
        fourier_dma_kernel<<<dim3(16, 1, 32), 256, 0, stream>>>(
            x, pkl, pkh, part);
        combine_kernel<<<dim3(BATCH / 64, OUTDIM / 64), 256, 0, stream>>>(
            x, bw, part, out, 32);
    } else {
        // fallback: round-2 path, auto-shrunk split count
        __hip_bfloat16* part = (__hip_bfloat16*)d_ws;
        int S = 32;
        while (S > 1 && (size_t)S * per > ws_size) S >>= 1;
        const int ips = INDIM / S;
        fourier_kernel_fb<<<dim3(BATCH / 256, OUTDIM / 128, S), 256, 0, stream>>>(
            x, fc, part, ips);
        combine_kernel<<<dim3(BATCH / 64, OUTDIM / 64), 256, 0, stream>>>(
            x, bw, part, out, S);
    }
}

// Round 17
// 214.614 us; speedup vs baseline: 1.0888x; 1.0888x over previous
//
#include <hip/hip_runtime.h>
#include <hip/hip_bf16.h>
#include <cstdint>

#define BATCH   2048
#define INDIM   256
#define OUTDIM  256
#define KGRID   300   // fourier modes k = 1..300
#define NCHUNK  10    // chunks of 32 k (last padded)

typedef __attribute__((ext_vector_type(4))) float f32x4;
typedef __attribute__((ext_vector_type(2))) float f32x2;
typedef __attribute__((ext_vector_type(8))) short bf16x8;

__device__ __forceinline__ uint32_t pack_bf16x2(float lo, float hi) {
    union { __hip_bfloat162 h; uint32_t u; } cv;
    cv.h = __float22bfloat162_rn(make_float2(lo, hi));
    return cv.u;
}

__device__ __forceinline__ float bfu2f(unsigned short u) {
    union { unsigned short s[2]; float f; } c; c.s[0] = 0; c.s[1] = u; return c.f;
}

// packed fp32x2 FMA with negated addend: d = a*b - c   (one VOP3P instr)
__device__ __forceinline__ f32x2 pk_fma_sub(f32x2 a, f32x2 b, f32x2 c) {
    f32x2 d;
    asm("v_pk_fma_f32 %0, %1, %2, %3 neg_lo:[0,0,1] neg_hi:[0,0,1]"
        : "=v"(d) : "v"(a), "v"(b), "v"(c));
    return d;
}

__device__ __forceinline__ void load_lds16(const void* g, void* l) {
    __builtin_amdgcn_global_load_lds(
        (const __attribute__((address_space(1))) void*)g,
        (__attribute__((address_space(3))) void*)l, 16, 0, 0);
}

__device__ __forceinline__ bf16x8 zero_frag() {
    union { uint32_t u[4]; bf16x8 v; } z = {{0u, 0u, 0u, 0u}};
    return z.v;
}

// Generate one A-fragment: 4 consecutive k of (cos,sin) bf16 pairs starting
// at seed (ck,sk); Chebyshev forward recurrence with T2 = 2 cos(theta).
__device__ __forceinline__ bf16x8 gen_frag(float ck, float sk,
                                           float c1, float s1) {
    float cp = __builtin_fmaf(ck, c1,  sk * s1);   // value at k-1
    float sp = __builtin_fmaf(sk, c1, -ck * s1);
    f32x2 C; C.x = ck; C.y = sk;
    f32x2 P; P.x = cp; P.y = sp;
    f32x2 T2; T2.x = c1 + c1; T2.y = c1 + c1;
    union { uint32_t u[4]; bf16x8 v; } r;
    #pragma unroll
    for (int q = 0; q < 4; ++q) {
        r.u[q] = pack_bf16x2(C.x, C.y);
        f32x2 N = pk_fma_sub(T2, C, P);
        P = C; C = N;
    }
    return r.v;
}

// packed coeff tensor: [i][ch][j][sub] of uint4 (4 k-values, (cos,sin) bf16
// pairs); position sub holds k-group (sub ^ (j & 7)) -> pre-applied swizzle.
#define PACKED_U4 ((size_t)INDIM * NCHUNK * OUTDIM * 8)       // 5,242,880
#define PACKED_BYTES (PACKED_U4 * 16)                         // 83.9 MB
#define PART_BYTES ((size_t)32 * BATCH * OUTDIM * 2)          // bf16, 33.5 MB

// ---------------------------------------------------------------------------
// Kernel 0: pack fc (fp32 [2][j][i][k]) -> bf16 pre-swizzled [i][ch][j][sub]
// ---------------------------------------------------------------------------
__global__ __launch_bounds__(256) void pack_kernel(
    const float* __restrict__ fc, uint4* __restrict__ pk)
{
    size_t tidg = (size_t)blockIdx.x * 256 + threadIdx.x;   // one uint4 each
    int sub = tidg & 7;
    int j   = (tidg >> 3) & 255;
    int ich = (int)(tidg >> 11);        // i*10 + ch, 0..2559
    int ch  = ich % NCHUNK;
    int i   = ich / NCHUNK;
    int kb  = ch * 32 + (sub ^ (j & 7)) * 4;
    if (kb > KGRID - 4) kb = KGRID - 4;   // clamp; A=0 kills padded kk
    const float* pc = fc + ((size_t)j * INDIM + i) * KGRID + kb;
    const float* ps = pc + (size_t)OUTDIM * INDIM * KGRID;
    float4 vc = *reinterpret_cast<const float4*>(pc);
    float4 vs = *reinterpret_cast<const float4*>(ps);
    uint4 wv;
    wv.x = pack_bf16x2(vc.x, vs.x);
    wv.y = pack_bf16x2(vc.y, vs.y);
    wv.z = pack_bf16x2(vc.z, vs.z);
    wv.w = pack_bf16x2(vc.w, vs.w);
    pk[tidg] = wv;
}

// ---------------------------------------------------------------------------
// Kernel 1 (main): fourier partials via MFMA. Measured optimum of 12
// structural variants (rounds 2-16): block = 128 b-rows x 256 j, 4 waves of
// 32 rows x 256 j (in-register A-gen, zero duplication), full-width B via
// global_load_lds DMA double-buffer, ONE barrier per iteration:
//   { __syncthreads  -> drains DMA(t) [issued a full iter ago, ~free] and
//                       releases buf[(t+1)&1] [its readers ran in iter t-1];
//     issue DMA(t+1); A-gen; 64 MFMA on buf[t&1]; }
// Partials stored bf16 (WRITE 65.7 -> 32.9 MB; halves combine reads).
// Pipe audit: LDS ~80% (binding), MFMA 52%, VALU 40%, issue ~90%.
// Grid 16 x 1 x 32 = 512 blocks (XCD-chunked swizzle), 2 blocks/CU.
// ---------------------------------------------------------------------------
__global__ __launch_bounds__(256, 2) void fourier_dma_kernel(
    const float* __restrict__ x, const uint4* __restrict__ pk,
    __hip_bfloat16* __restrict__ part)
{
    __shared__ uint4 Bbuf[2][256][8];   // 64 KiB double-buffered DMA dest

    const int tid = threadIdx.x;
    // XCD-chunked bijective remap (512 = 8 XCD x 64)
    const int flat = blockIdx.x + (blockIdx.z << 4);
    const int L  = (flat & 7) * 64 + (flat >> 3);
    const int b0 = (L & 15) * 128;
    const int z  = L >> 4;              // i-split 0..31
    const int i0 = z * 8;

    const int lane = tid & 63, wave = tid >> 6;
    const int wrow = wave * 32;         // this wave's first b-row in block
    const int lrow = lane & 15, lgrp = lane >> 4;
    const int q8 = wave * 8;            // this wave's 8 DMA issues

    f32x4 acc[2][16] = {};              // [mf][nf], 128 regs

    // per-row (mf) generator state
    float thn[2];                       // prefetched theta for current/next il
    float c1[2], s1[2];                 // sincos(theta)
    float c16[2], s16[2];               // sincos(16 theta)
    float cS[2], sS[2];                 // running seed

    #pragma unroll
    for (int mf = 0; mf < 2; ++mf)
        thn[mf] = x[(size_t)(b0 + wrow + mf * 16 + lrow) * INDIM + i0];

    // prologue: DMA B(il=0, ch=0) into Bbuf[0]
    {
        const uint4* src = pk + (size_t)(i0 * NCHUNK) * 2048;
        char* dst = (char*)&Bbuf[0][0][0];
        #pragma unroll
        for (int q = 0; q < 8; ++q)
            load_lds16(src + (q8 + q) * 64 + lane, dst + (q8 + q) * 1024);
    }

    int il = 0, ch = 0;
    #pragma unroll 1
    for (int t = 0; t < 8 * NCHUNK; ++t) {
        // ---- single barrier: drains DMA(t), releases buf[(t+1)&1] ----
        __syncthreads();
        // ---- issue DMA for t+1 (in flight across A-gen + MFMA) ----
        {
            int il2 = il, ch2 = ch + 1;
            if (ch2 == NCHUNK) { ch2 = 0; il2 = (il + 1 < 8) ? il + 1 : il; }
            const uint4* src = pk + (size_t)((i0 + il2) * NCHUNK + ch2) * 2048;
            char* dst = (char*)&Bbuf[(t + 1) & 1][0][0];
            #pragma unroll
            for (int q = 0; q < 8; ++q)
                load_lds16(src + (q8 + q) * 64 + lane, dst + (q8 + q) * 1024);
        }
        // ---- per-il seed init (every 10th iter) ----
        if (ch == 0) {
            const float flg = (float)(lgrp * 4);
            #pragma unroll
            for (int mf = 0; mf < 2; ++mf) {
                float th = thn[mf];
                __sincosf(th, &s1[mf], &c1[mf]);
                __sincosf(16.f * th, &s16[mf], &c16[mf]);
                float a0 = __builtin_fmaf(flg, th, th);   // (lgrp*4+1)*theta
                __sincosf(a0, &sS[mf], &cS[mf]);
            }
            int iln = (il + 1 < 8) ? il + 1 : il;         // prefetch next theta
            #pragma unroll
            for (int mf = 0; mf < 2; ++mf)
                thn[mf] = x[(size_t)(b0 + wrow + mf * 16 + lrow) * INDIM
                            + i0 + iln];
        }
        // ---- A-gen: 4 fragments in registers (2 rows x 2 k-halves) ----
        bf16x8 af[2][2];                 // [s][mf]
        #pragma unroll
        for (int mf = 0; mf < 2; ++mf) {
            af[0][mf] = gen_frag(cS[mf], sS[mf], c1[mf], s1[mf]);
            float ck = __builtin_fmaf(cS[mf], c16[mf], -sS[mf] * s16[mf]);
            float sk = __builtin_fmaf(sS[mf], c16[mf],  cS[mf] * s16[mf]);
            af[1][mf] = gen_frag(ck, sk, c1[mf], s1[mf]);
            // advance seed to next chunk: rotate by 16*theta again (=32 total)
            cS[mf] = __builtin_fmaf(ck, c16[mf], -sk * s16[mf]);
            sS[mf] = __builtin_fmaf(sk, c16[mf],  ck * s16[mf]);
        }
        if (ch == NCHUNK - 1) {          // zero padded k >= 300
            #pragma unroll
            for (int mf = 0; mf < 2; ++mf) {
                af[0][mf] = (lgrp == 3) ? zero_frag() : af[0][mf];
                af[1][mf] = zero_frag();  // k >= 304 entirely
            }
        }
        // ---- 64 MFMA on tile t (full 256-j width per wave) ----
        __builtin_amdgcn_s_setprio(1);
        #pragma unroll
        for (int s = 0; s < 2; ++s) {
            const int swz = (s * 4 + lgrp) ^ (lrow & 7);   // loop-invariant per s
            #pragma unroll
            for (int g = 0; g < 4; ++g) {                  // 4 groups of 4 nf
                bf16x8 bfr[4];
                #pragma unroll
                for (int q = 0; q < 4; ++q) {
                    const int jl = (g * 4 + q) * 16 + lrow;
                    uint4 tv = Bbuf[t & 1][jl][swz];
                    bfr[q] = *reinterpret_cast<bf16x8*>(&tv);
                }
                #pragma unroll
                for (int mf = 0; mf < 2; ++mf)
                    #pragma unroll
                    for (int q = 0; q < 4; ++q)
                        acc[mf][g * 4 + q] = __builtin_amdgcn_mfma_f32_16x16x32_bf16(
                            af[s][mf], bfr[q], acc[mf][g * 4 + q], 0, 0, 0);
            }
        }
        __builtin_amdgcn_s_setprio(0);
        if (++ch == NCHUNK) { ch = 0; ++il; }
    }

    // epilogue: per-split bf16 partial tile (single writer per element)
    __hip_bfloat16* pws = part + (size_t)z * BATCH * OUTDIM;
    #pragma unroll
    for (int mf = 0; mf < 2; ++mf)
        #pragma unroll
        for (int nf = 0; nf < 16; ++nf)
            #pragma unroll
            for (int r = 0; r < 4; ++r) {
                int b = b0 + wrow + mf * 16 + lgrp * 4 + r;
                int j = nf * 16 + lrow;
                pws[(size_t)b * OUTDIM + j] = __float2bfloat16(acc[mf][nf][r]);
            }
}

// ---------------------------------------------------------------------------
// Fallback fourier kernel (round-2, reg-staged from fc): ws too small.
// ---------------------------------------------------------------------------
__global__ __launch_bounds__(256, 2) void fourier_kernel_fb(
    const float* __restrict__ x, const float* __restrict__ fc,
    __hip_bfloat16* __restrict__ ws, int ips)
{
    __shared__ uint4 Abuf[2][128][8];
    __shared__ uint4 Bbuf[128][8];

    const int tid  = threadIdx.x;
    const int b0   = blockIdx.x * 256;
    const int j0   = blockIdx.y * 128;
    const int i0   = blockIdx.z * ips;

    const int lane = tid & 63, wave = tid >> 6;
    const int wm   = wave >> 1, wn = wave & 1;
    const int lrow = lane & 15, lgrp = lane >> 4;
    const int grow = tid >> 1,  gh = tid & 1;

    f32x4 acc[2][4][4] = {};

    #pragma unroll 1
    for (int il = 0; il < ips; ++il) {
        const int i = i0 + il;
        float th[2], c1[2], s1[2], t2[2];
        th[0] = x[(size_t)(b0 + grow)       * INDIM + i];
        th[1] = x[(size_t)(b0 + 128 + grow) * INDIM + i];
        #pragma unroll
        for (int m = 0; m < 2; ++m) {
            __sincosf(th[m], &s1[m], &c1[m]);
            t2[m] = 2.f * c1[m];
        }
        #pragma unroll 1
        for (int ch = 0; ch < NCHUNK; ++ch) {
            #pragma unroll
            for (int r = 0; r < 4; ++r) {
                int flat = r * 256 + tid;
                int jl = flat >> 3, sub = flat & 7;
                int kb = ch * 32 + sub * 4;
                if (kb > KGRID - 4) kb = KGRID - 4;
                const float* pc = fc + ((size_t)(j0 + jl) * INDIM + i) * KGRID + kb;
                const float* ps = pc + (size_t)OUTDIM * INDIM * KGRID;
                float4 vc = *reinterpret_cast<const float4*>(pc);
                float4 vs = *reinterpret_cast<const float4*>(ps);
                uint4 wv;
                wv.x = pack_bf16x2(vc.x, vs.x);
                wv.y = pack_bf16x2(vc.y, vs.y);
                wv.z = pack_bf16x2(vc.z, vs.z);
                wv.w = pack_bf16x2(vc.w, vs.w);
                Bbuf[jl][sub ^ (jl & 7)] = wv;
            }
            #pragma unroll
            for (int m = 0; m < 2; ++m) {
                const int k0 = ch * 32 + gh * 16;
                float ck, sk;
                __sincosf(th[m] * (float)(k0 + 1), &sk, &ck);
                float cp = __builtin_fmaf(ck, c1[m],  sk * s1[m]);
                float sp = __builtin_fmaf(sk, c1[m], -ck * s1[m]);
                const int swz = grow & 7;
                #pragma unroll
                for (int c = 0; c < 4; ++c) {
                    uint32_t uu[4];
                    #pragma unroll
                    for (int qq = 0; qq < 4; ++qq) {
                        const int kidx = k0 + c * 4 + qq;
                        float cc = (kidx < KGRID) ? ck : 0.f;
                        float ss = (kidx < KGRID) ? sk : 0.f;
                        uu[qq] = pack_bf16x2(cc, ss);
                        float cn = __builtin_fmaf(t2[m], ck, -cp);
                        float sn = __builtin_fmaf(t2[m], sk, -sp);
                        cp = ck; sp = sk; ck = cn; sk = sn;
                    }
                    Abuf[m][grow][(gh * 4 + c) ^ swz] =
                        make_uint4(uu[0], uu[1], uu[2], uu[3]);
                }
            }
            __syncthreads();
            #pragma unroll
            for (int s = 0; s < 2; ++s) {
                bf16x8 bfr[4];
                #pragma unroll
                for (int nf = 0; nf < 4; ++nf) {
                    const int jl = wn * 64 + nf * 16 + lrow;
                    uint4 tv = Bbuf[jl][(s * 4 + lgrp) ^ (jl & 7)];
                    bfr[nf] = *reinterpret_cast<bf16x8*>(&tv);
                }
                #pragma unroll
                for (int m = 0; m < 2; ++m) {
                    #pragma unroll
                    for (int mf = 0; mf < 4; ++mf) {
                        const int rowA = wm * 64 + mf * 16 + lrow;
                        uint4 tv = Abuf[m][rowA][(s * 4 + lgrp) ^ (rowA & 7)];
                        bf16x8 af = *reinterpret_cast<bf16x8*>(&tv);
                        #pragma unroll
                        for (int nf = 0; nf < 4; ++nf)
                            acc[m][mf][nf] = __builtin_amdgcn_mfma_f32_16x16x32_bf16(
                                af, bfr[nf], acc[m][mf][nf], 0, 0, 0);
                    }
                }
            }
            __syncthreads();
        }
    }

    __hip_bfloat16* pws = ws + (size_t)blockIdx.z * BATCH * OUTDIM;
    #pragma unroll
    for (int m = 0; m < 2; ++m)
        #pragma unroll
        for (int mf = 0; mf < 4; ++mf)
            #pragma unroll
            for (int nf = 0; nf < 4; ++nf)
                #pragma unroll
                for (int r = 0; r < 4; ++r) {
                    int b = b0 + m * 128 + wm * 64 + mf * 16 + lgrp * 4 + r;
                    int j = j0 + wn * 64 + nf * 16 + lrow;
                    pws[(size_t)b * OUTDIM + j] =
                        __float2bfloat16(acc[m][mf][nf][r]);
                }
}

// ---------------------------------------------------------------------------
// Kernel 2: out[b,j] = silu(x[b,:] @ W[:,j]) + sum_s part[s][b][j]  (bf16)
// ---------------------------------------------------------------------------
__global__ __launch_bounds__(256) void combine_kernel(
    const float* __restrict__ x, const float* __restrict__ w,
    const __hip_bfloat16* __restrict__ part, float* __restrict__ out,
    int nsplit)
{
    __shared__ float Xs[64][16];
    __shared__ float Wt[16][68];

    const int tid = threadIdx.x;
    const int b0 = blockIdx.x * 64;
    const int j0 = blockIdx.y * 64;
    const int tx = tid & 15, ty = tid >> 4;

    float acc[4][4] = {};

    for (int kb = 0; kb < INDIM; kb += 16) {
        {
            int m = tid >> 2, kq = (tid & 3) * 4;
            float4 v = *reinterpret_cast<const float4*>(
                &x[(size_t)(b0 + m) * INDIM + kb + kq]);
            Xs[m][kq+0] = v.x; Xs[m][kq+1] = v.y; Xs[m][kq+2] = v.z; Xs[m][kq+3] = v.w;
        }
        {
            int kr = tid >> 4, jc = (tid & 15) * 4;
            float4 v = *reinterpret_cast<const float4*>(
                &w[(size_t)(kb + kr) * OUTDIM + j0 + jc]);
            Wt[kr][jc+0] = v.x; Wt[kr][jc+1] = v.y; Wt[kr][jc+2] = v.z; Wt[kr][jc+3] = v.w;
        }
        __syncthreads();
        #pragma unroll
        for (int kk = 0; kk < 16; ++kk) {
            float a[4], b[4];
            #pragma unroll
            for (int q = 0; q < 4; ++q) { a[q] = Xs[ty*4+q][kk]; b[q] = Wt[kk][tx*4+q]; }
            #pragma unroll
            for (int q = 0; q < 4; ++q)
                #pragma unroll
                for (int p = 0; p < 4; ++p)
                    acc[q][p] = __builtin_fmaf(a[q], b[p], acc[q][p]);
        }
        __syncthreads();
    }

    float psum[4][4] = {};
    for (int s = 0; s < nsplit; ++s) {
        const __hip_bfloat16* base = part + (size_t)s * BATCH * OUTDIM;
        #pragma unroll
        for (int q = 0; q < 4; ++q) {
            ushort4 pv = *reinterpret_cast<const ushort4*>(
                &base[(size_t)(b0 + ty*4 + q) * OUTDIM + j0 + tx*4]);
            psum[q][0] += bfu2f(pv.x); psum[q][1] += bfu2f(pv.y);
            psum[q][2] += bfu2f(pv.z); psum[q][3] += bfu2f(pv.w);
        }
    }

    #pragma unroll
    for (int q = 0; q < 4; ++q)
        #pragma unroll
        for (int p = 0; p < 4; ++p) {
            float v = acc[q][p];
            float sv = v / (1.f + __expf(-v));
            out[(size_t)(b0 + ty*4 + q) * OUTDIM + (j0 + tx*4 + p)] =
                sv + psum[q][p];
        }
}

// ---------------------------------------------------------------------------
extern "C" void kernel_launch(void* const* d_in, const int* in_sizes, int n_in,
                              void* d_out, int out_size, void* d_ws, size_t ws_size,
                              hipStream_t stream) {
    const float* x  = (const float*)d_in[0];   // [2048, 256]
    const float* bw = (const float*)d_in[1];   // [256, 256]
    const float* fc = (const float*)d_in[2];   // [2, 256, 256, 300]
    float* out = (float*)d_out;                // [2048, 256]

    const size_t per = (size_t)BATCH * OUTDIM * 2;   // 1 MB/split (bf16)

    if (ws_size >= PACKED_BYTES + PART_BYTES) {
        // main path: pack -> DMA fourier -> combine
        uint4* pk = (uint4*)d_ws;
        __hip_bfloat16* part = (__hip_bfloat16*)((char*)d_ws + PACKED_BYTES);
        pack_kernel<<<(int)(PACKED_U4 / 256), 256, 0, stream>>>(fc, pk);
        fourier_dma_kernel<<<dim3(16, 1, 32), 256, 0, stream>>>(x, pk, part);
        combine_kernel<<<dim3(BATCH / 64, OUTDIM / 64), 256, 0, stream>>>(
            x, bw, part, out, 32);
    } else {
        // fallback: round-2 path, auto-shrunk split count
        __hip_bfloat16* part = (__hip_bfloat16*)d_ws;
        int S = 32;
        while (S > 1 && (size_t)S * per > ws_size) S >>= 1;
        const int ips = INDIM / S;
        fourier_kernel_fb<<<dim3(BATCH / 256, OUTDIM / 128, S), 256, 0, stream>>>(
            x, fc, part, ips);
        combine_kernel<<<dim3(BATCH / 64, OUTDIM / 64), 256, 0, stream>>>(
            x, bw, part, out, S);
    }
}